// Round 9
// baseline (175.326 us; speedup 1.0000x reference)
//
#include <hip/hip_runtime.h>

#define N_NODES 50000
#define H_DIM 96
#define EPS 1e-5f

typedef unsigned int uint32;
typedef __attribute__((ext_vector_type(8))) short short8;
typedef __attribute__((ext_vector_type(4))) float f32x4;

// ---- bf16 pack helper (RNE) ----
__device__ __forceinline__ uint32 bf16_rne(float f) {
    uint32 b = __float_as_uint(f);
    return (b + 0x7fffu + ((b >> 16) & 1u)) >> 16;
}
__device__ __forceinline__ float bf_lo(uint32 u) { return __uint_as_float(u << 16); }
__device__ __forceinline__ float bf_hi(uint32 u) { return __uint_as_float(u & 0xffff0000u); }

// ---------------- CSR build ----------------

// zero deg + pack W1/W2 transposed bf16 (fused)
__global__ void zero_wprep_kernel(int* __restrict__ deg, int N,
                                  const float* __restrict__ W1, uint32* __restrict__ B1,
                                  const float* __restrict__ W2, uint32* __restrict__ B2) {
    int i = blockIdx.x * 256 + threadIdx.x;
    if (i < N) deg[i] = 0;
    if (i < 96 * 64) {                      // W1: K=128, KP2=68
        int n = i / 64, k = i % 64;
        B1[n * 68 + k] = bf16_rne(W1[(size_t)(2 * k) * 96 + n]) |
                         (bf16_rne(W1[(size_t)(2 * k + 1) * 96 + n]) << 16);
    } else if (i < 96 * 64 + 96 * 48) {     // W2: K=96, KP2=52
        int t = i - 96 * 64;
        int n = t / 48, k = t % 48;
        B2[n * 52 + k] = bf16_rne(W2[(size_t)(2 * k) * 96 + n]) |
                         (bf16_rne(W2[(size_t)(2 * k + 1) * 96 + n]) << 16);
    }
}

// pass 1: degree count + per-edge rank within its dst row (one atomic/edge total)
__global__ void rank_kernel(const int* __restrict__ dst, int* __restrict__ deg,
                            int* __restrict__ rank, int E) {
    int e = blockIdx.x * 256 + threadIdx.x;
    if (e < E) {
        int d = __builtin_nontemporal_load(&dst[e]);
        int r = atomicAdd(&deg[d], 1);
        __builtin_nontemporal_store(r, &rank[e]);
    }
}

// stage 1: per-block exclusive scan (into rowptr) + block sums
__global__ __launch_bounds__(256) void scan_blocks(const int* __restrict__ deg,
                                                   int* __restrict__ rowptr,
                                                   int* __restrict__ bsum, int n) {
    __shared__ int wsum[4];
    int i = blockIdx.x * 256 + threadIdx.x;
    int lane = threadIdx.x & 63, w = threadIdx.x >> 6;
    int v = (i < n) ? deg[i] : 0;
    int s = v;
#pragma unroll
    for (int o = 1; o < 64; o <<= 1) { int t = __shfl_up(s, o); if (lane >= o) s += t; }
    if (lane == 63) wsum[w] = s;
    __syncthreads();
    int off = 0;
#pragma unroll
    for (int k = 0; k < 4; ++k) if (k < w) off += wsum[k];
    s += off;
    if (i < n) rowptr[i] = s - v;               // exclusive within block
    if (threadIdx.x == 255) bsum[blockIdx.x] = s;
}

// stage 2+3 merged: every block scans bsum redundantly, applies its offset; dinv
__global__ __launch_bounds__(256) void finalize2_kernel(int* __restrict__ rowptr,
                                                        const int* __restrict__ bsum,
                                                        const int* __restrict__ deg,
                                                        float* __restrict__ dinv,
                                                        int n, int E, int nChunk) {
    __shared__ int wsum[4];
    __shared__ int soff[256];
    int tid = threadIdx.x;
    int lane = tid & 63, w = tid >> 6;
    int v = (tid < nChunk) ? bsum[tid] : 0;
    int s = v;
#pragma unroll
    for (int o = 1; o < 64; o <<= 1) { int t = __shfl_up(s, o); if (lane >= o) s += t; }
    if (lane == 63) wsum[w] = s;
    __syncthreads();
    int off = 0;
#pragma unroll
    for (int k = 0; k < 4; ++k) if (k < w) off += wsum[k];
    soff[tid] = s + off - v;                    // exclusive scan of bsum
    __syncthreads();
    int blockOff = soff[blockIdx.x];
    int i = blockIdx.x * 256 + tid;
    if (i < n) {
        rowptr[i] += blockOff;
        dinv[i] = rsqrtf((float)(deg[i] + 1));  // +1 = self loop
    }
    if (i == 0) rowptr[n] = E;
}

// pass 2: pure scatter, no atomics
__global__ void fill_kernel(const int* __restrict__ src, const int* __restrict__ dst,
                            const int* __restrict__ rank, const int* __restrict__ rowptr,
                            int* __restrict__ col, int E) {
    int e = blockIdx.x * 256 + threadIdx.x;
    if (e < E) {
        int d = __builtin_nontemporal_load(&dst[e]);
        int r = __builtin_nontemporal_load(&rank[e]);
        int sv = __builtin_nontemporal_load(&src[e]);
        __builtin_nontemporal_store(sv, &col[rowptr[d] + r]);
    }
}

// ---- MFMA GEMM: Hs[row] = bf16x2-packed (A @ W) * dinv[row] ----

template <int K, bool AF32>
__global__ __launch_bounds__(256) void gemm_mfma(const void* __restrict__ Aptr,
                                                 const uint32* __restrict__ Bt,
                                                 const float* __restrict__ dinv,
                                                 uint32* __restrict__ Hs, int N) {
    constexpr int KP2 = (K + 8) / 2;          // uints per padded row (68 / 52)
    __shared__ uint32 As[64 * KP2];
    __shared__ uint32 Bs[96 * KP2];
    int tid = threadIdx.x;
    int rowbase = blockIdx.x * 64;

    if constexpr (AF32) {
        const float* A = (const float*)Aptr;
        for (int f = tid; f < 64 * (K / 4); f += 256) {
            int r = f / (K / 4), q = f % (K / 4);
            int row = rowbase + r;
            float4 v = make_float4(0.f, 0.f, 0.f, 0.f);
            if (row < N) v = *reinterpret_cast<const float4*>(A + (size_t)row * K + q * 4);
            As[r * KP2 + q * 2]     = bf16_rne(v.x) | (bf16_rne(v.y) << 16);
            As[r * KP2 + q * 2 + 1] = bf16_rne(v.z) | (bf16_rne(v.w) << 16);
        }
    } else {
        const uint32* A = (const uint32*)Aptr;
        for (int f = tid; f < 64 * (K / 8); f += 256) {
            int r = f / (K / 8), s = f % (K / 8);
            int row = rowbase + r;
            uint4 v = make_uint4(0, 0, 0, 0);
            if (row < N) v = *reinterpret_cast<const uint4*>(A + (size_t)row * (K / 2) + s * 4);
            *reinterpret_cast<uint4*>(&As[r * KP2 + s * 4]) = v;
        }
    }
    for (int f = tid; f < 96 * KP2 / 4; f += 256) {
        *reinterpret_cast<uint4*>(&Bs[f * 4]) = *reinterpret_cast<const uint4*>(Bt + f * 4);
    }
    __syncthreads();

    int l = tid & 63, w = tid >> 6;
    int l15 = l & 15, lq = l >> 4;

    f32x4 acc[6];
#pragma unroll
    for (int j = 0; j < 6; ++j) acc[j] = (f32x4){0.f, 0.f, 0.f, 0.f};

    const uint32* arow = &As[(w * 16 + l15) * KP2 + lq * 4];   // k = lq*8
#pragma unroll
    for (int kc = 0; kc < K / 32; ++kc) {
        short8 a = *reinterpret_cast<const short8*>(arow + kc * 16);
#pragma unroll
        for (int j = 0; j < 6; ++j) {
            short8 b = *reinterpret_cast<const short8*>(&Bs[(j * 16 + l15) * KP2 + lq * 4 + kc * 16]);
            acc[j] = __builtin_amdgcn_mfma_f32_16x16x32_bf16(a, b, acc[j], 0, 0, 0);
        }
    }

#pragma unroll
    for (int r = 0; r < 4; ++r) {
        int row = rowbase + w * 16 + lq * 4 + r;
        float di = (row < N) ? dinv[row] : 0.f;
#pragma unroll
        for (int j = 0; j < 6; ++j) {
            float v = acc[j][r] * di;
            float vp = __shfl_xor(v, 1);
            if (row < N && !(l & 1)) {
                Hs[(size_t)row * 48 + (j * 16 + l15) / 2] = bf16_rne(v) | (bf16_rne(vp) << 16);
            }
        }
    }
}

// ---------- fused: aggregate (sym-norm) + bias + LayerNorm + PReLU ----------
// One wave = TWO nodes (2 x 32-lane halves); lane hl<24 owns 4 channels (dwordx2).
// Double-buffered 8-edge batches: batch b+1's gathers issue before batch b is
// consumed (statically-indexed ua/ub). col stream is NT-loaded to keep the
// gather table resident in L2.

template <bool PACK_OUT>
__global__ __launch_bounds__(256) void agg_ln_prelu(const uint32* __restrict__ Hs,
                                                    const float* __restrict__ dinv,
                                                    const int* __restrict__ rowptr,
                                                    const int* __restrict__ col,
                                                    const float* __restrict__ bias,
                                                    const float* __restrict__ gamma,
                                                    const float* __restrict__ beta,
                                                    const float* __restrict__ alpha,
                                                    void* __restrict__ outv, int N) {
    int tid = threadIdx.x;
    int w = tid >> 6, lane = tid & 63;
    int half = lane >> 5, hl = lane & 31;
    int nodebase = blockIdx.x * 8 + w * 2;
    if (nodebase >= N) return;                 // both halves OOB
    int node = nodebase + half;
    int hc = min(hl, 23);                      // clamped channel-quad index
    bool active = (hl < 24) && (node < N);

    float a0 = 0.f, a1 = 0.f, a2 = 0.f, a3 = 0.f;
    float b0 = 0.f, b1 = 0.f, b2 = 0.f, b3 = 0.f;

    int e0 = 0, e1 = 0;
    if (node < N) { e0 = rowptr[node]; e1 = rowptr[node + 1]; }
    const uint32* hp = Hs + 2 * hc;            // lane's column offset

    if (node < N) {
        uint2 us = *reinterpret_cast<const uint2*>(hp + (size_t)node * 48);   // self
        a0 = bf_lo(us.x); a1 = bf_hi(us.x); a2 = bf_lo(us.y); a3 = bf_hi(us.y);
    }

    int nb = (e1 - e0 + 7) >> 3;               // number of 8-edge batches
    uint2 ua[8], ub[8];

    auto load_batch = [&](uint2 (&u)[8], int bi) {
        int base = e0 + bi * 8;
#pragma unroll
        for (int t = 0; t < 8; ++t) {
            int ee = min(base + t, e1 - 1);
            int j = __builtin_nontemporal_load(&col[ee]);
            uint2 v = *reinterpret_cast<const uint2*>(hp + (size_t)j * 48);
            if (base + t >= e1) { v.x = 0u; v.y = 0u; }
            u[t] = v;
        }
    };
    auto consume = [&](uint2 (&u)[8]) {
#pragma unroll
        for (int t = 0; t < 8; ++t) {
            if (t & 1) { b0 += bf_lo(u[t].x); b1 += bf_hi(u[t].x); b2 += bf_lo(u[t].y); b3 += bf_hi(u[t].y); }
            else       { a0 += bf_lo(u[t].x); a1 += bf_hi(u[t].x); a2 += bf_lo(u[t].y); a3 += bf_hi(u[t].y); }
        }
    };

    if (nb > 0) {
        load_batch(ua, 0);
        int b = 0;
        while (true) {
            if (b + 1 < nb) load_batch(ub, b + 1);
            consume(ua);
            ++b;
            if (b >= nb) break;
            if (b + 1 < nb) load_batch(ua, b + 1);
            consume(ub);
            ++b;
            if (b >= nb) break;
        }
    }

    float di = (node < N) ? dinv[node] : 0.f;
    float4 bs = *reinterpret_cast<const float4*>(bias + 4 * hc);
    float c0 = (a0 + b0) * di + bs.x;
    float c1 = (a1 + b1) * di + bs.y;
    float c2 = (a2 + b2) * di + bs.z;
    float c3 = (a3 + b3) * di + bs.w;

    // LayerNorm over 96 channels: butterfly within the 32-lane half
    float s1 = active ? (c0 + c1) + (c2 + c3) : 0.f;
    float s2 = active ? (c0 * c0 + c1 * c1) + (c2 * c2 + c3 * c3) : 0.f;
#pragma unroll
    for (int o = 16; o > 0; o >>= 1) {
        s1 += __shfl_xor(s1, o);
        s2 += __shfl_xor(s2, o);
    }

    if (active) {
        float mu = s1 * (1.f / 96.f);
        float var = s2 * (1.f / 96.f) - mu * mu;
        float rstd = rsqrtf(var + EPS);
        float4 gm = *reinterpret_cast<const float4*>(gamma + 4 * hc);
        float4 bt = *reinterpret_cast<const float4*>(beta + 4 * hc);
        float4 al = *reinterpret_cast<const float4*>(alpha + 4 * hc);
        float ln0 = (c0 - mu) * rstd * gm.x + bt.x;
        float ln1 = (c1 - mu) * rstd * gm.y + bt.y;
        float ln2 = (c2 - mu) * rstd * gm.z + bt.z;
        float ln3 = (c3 - mu) * rstd * gm.w + bt.w;
        float o0 = (ln0 >= 0.f) ? ln0 : al.x * ln0;
        float o1 = (ln1 >= 0.f) ? ln1 : al.y * ln1;
        float o2 = (ln2 >= 0.f) ? ln2 : al.z * ln2;
        float o3 = (ln3 >= 0.f) ? ln3 : al.w * ln3;
        if constexpr (PACK_OUT) {
            uint2 pv;
            pv.x = bf16_rne(o0) | (bf16_rne(o1) << 16);
            pv.y = bf16_rne(o2) | (bf16_rne(o3) << 16);
            *reinterpret_cast<uint2*>((uint32*)outv + (size_t)node * 48 + 2 * hl) = pv;
        } else {
            float4 ov; ov.x = o0; ov.y = o1; ov.z = o2; ov.w = o3;
            *reinterpret_cast<float4*>((float*)outv + (size_t)node * 96 + 4 * hl) = ov;
        }
    }
}

// ---------------- launch ----------------

extern "C" void kernel_launch(void* const* d_in, const int* in_sizes, int n_in,
                              void* d_out, int out_size, void* d_ws, size_t ws_size,
                              hipStream_t stream) {
    const float* x   = (const float*)d_in[0];
    const int*   ei  = (const int*)d_in[1];
    const float* W1  = (const float*)d_in[2];
    const float* b1  = (const float*)d_in[3];
    const float* W2  = (const float*)d_in[4];
    const float* b2  = (const float*)d_in[5];
    const float* g1  = (const float*)d_in[6];
    const float* be1 = (const float*)d_in[7];
    const float* g2  = (const float*)d_in[8];
    const float* be2 = (const float*)d_in[9];
    const float* a   = (const float*)d_in[10];

    const int N = in_sizes[0] / 128;       // 50000
    const int E = in_sizes[1] / 2;         // 800000
    const int* src = ei;
    const int* dst = ei + E;
    const int nScanBlocks = (N + 255) / 256;

    char* ws = (char*)d_ws;
    size_t off = 0;
    auto carve = [&](size_t bytes) -> void* {
        void* p = ws + off;
        off += (bytes + 255) & ~(size_t)255;
        return p;
    };
    int*    deg    = (int*)carve((size_t)N * 4);
    int*    rowptr = (int*)carve((size_t)(N + 1) * 4);
    int*    bsum   = (int*)carve((size_t)nScanBlocks * 4);
    float*  dinv   = (float*)carve((size_t)N * 4);
    int*    rank   = (int*)carve((size_t)E * 4);
    int*    col    = (int*)carve((size_t)E * 4);
    uint32* hbuf   = (uint32*)carve((size_t)N * 48 * 4);   // bf16x2 gather table
    uint32* w1bt   = (uint32*)carve((size_t)96 * 68 * 4);  // W1^T bf16 padded
    uint32* w2bt   = (uint32*)carve((size_t)96 * 52 * 4);  // W2^T bf16 padded
    uint32* p1     = (uint32*)d_out;   // layer-1 bf16x2 activations (front of d_out)
    float*  outp   = (float*)d_out;

    zero_wprep_kernel<<<nScanBlocks, 256, 0, stream>>>(deg, N, W1, w1bt, W2, w2bt);
    rank_kernel<<<(E + 255) / 256, 256, 0, stream>>>(dst, deg, rank, E);
    scan_blocks<<<nScanBlocks, 256, 0, stream>>>(deg, rowptr, bsum, N);
    finalize2_kernel<<<nScanBlocks, 256, 0, stream>>>(rowptr, bsum, deg, dinv, N, E, nScanBlocks);
    fill_kernel<<<(E + 255) / 256, 256, 0, stream>>>(src, dst, rank, rowptr, col, E);

    // layer 1
    gemm_mfma<128, true><<<(N + 63) / 64, 256, 0, stream>>>(x, w1bt, dinv, hbuf, N);
    agg_ln_prelu<true><<<(N + 7) / 8, 256, 0, stream>>>(hbuf, dinv, rowptr, col, b1, g1, be1, a, p1, N);
    // layer 2
    gemm_mfma<96, false><<<(N + 63) / 64, 256, 0, stream>>>(p1, w2bt, dinv, hbuf, N);
    agg_ln_prelu<false><<<(N + 7) / 8, 256, 0, stream>>>(hbuf, dinv, rowptr, col, b2, g2, be2, a, outp, N);
}

// Round 10
// 153.202 us; speedup vs baseline: 1.1444x; 1.1444x over previous
//
#include <hip/hip_runtime.h>

#define N_NODES 50000
#define H_DIM 96
#define EPS 1e-5f

typedef unsigned int uint32;
typedef __attribute__((ext_vector_type(8))) short short8;
typedef __attribute__((ext_vector_type(4))) float f32x4;

// ---- bf16 pack helper (RNE) ----
__device__ __forceinline__ uint32 bf16_rne(float f) {
    uint32 b = __float_as_uint(f);
    return (b + 0x7fffu + ((b >> 16) & 1u)) >> 16;
}
__device__ __forceinline__ float bf_lo(uint32 u) { return __uint_as_float(u << 16); }
__device__ __forceinline__ float bf_hi(uint32 u) { return __uint_as_float(u & 0xffff0000u); }

// ---------------- CSR build ----------------

// zero deg + pack W1/W2 transposed bf16 (fused)
__global__ void zero_wprep_kernel(int* __restrict__ deg, int N,
                                  const float* __restrict__ W1, uint32* __restrict__ B1,
                                  const float* __restrict__ W2, uint32* __restrict__ B2) {
    int i = blockIdx.x * 256 + threadIdx.x;
    if (i < N) deg[i] = 0;
    if (i < 96 * 64) {                      // W1: K=128, KP2=68
        int n = i / 64, k = i % 64;
        B1[n * 68 + k] = bf16_rne(W1[(size_t)(2 * k) * 96 + n]) |
                         (bf16_rne(W1[(size_t)(2 * k + 1) * 96 + n]) << 16);
    } else if (i < 96 * 64 + 96 * 48) {     // W2: K=96, KP2=52
        int t = i - 96 * 64;
        int n = t / 48, k = t % 48;
        B2[n * 52 + k] = bf16_rne(W2[(size_t)(2 * k) * 96 + n]) |
                         (bf16_rne(W2[(size_t)(2 * k + 1) * 96 + n]) << 16);
    }
}

// pass 1: degree count + per-edge rank within its dst row (one atomic/edge total)
__global__ void rank_kernel(const int* __restrict__ dst, int* __restrict__ deg,
                            int* __restrict__ rank, int E) {
    int e = blockIdx.x * 256 + threadIdx.x;
    if (e < E) rank[e] = atomicAdd(&deg[dst[e]], 1);
}

// stage 1: per-block exclusive scan (into rowptr) + block sums
__global__ __launch_bounds__(256) void scan_blocks(const int* __restrict__ deg,
                                                   int* __restrict__ rowptr,
                                                   int* __restrict__ bsum, int n) {
    __shared__ int wsum[4];
    int i = blockIdx.x * 256 + threadIdx.x;
    int lane = threadIdx.x & 63, w = threadIdx.x >> 6;
    int v = (i < n) ? deg[i] : 0;
    int s = v;
#pragma unroll
    for (int o = 1; o < 64; o <<= 1) { int t = __shfl_up(s, o); if (lane >= o) s += t; }
    if (lane == 63) wsum[w] = s;
    __syncthreads();
    int off = 0;
#pragma unroll
    for (int k = 0; k < 4; ++k) if (k < w) off += wsum[k];
    s += off;
    if (i < n) rowptr[i] = s - v;               // exclusive within block
    if (threadIdx.x == 255) bsum[blockIdx.x] = s;
}

// stage 2+3 merged: every block scans bsum redundantly, applies its offset; dinv
__global__ __launch_bounds__(256) void finalize2_kernel(int* __restrict__ rowptr,
                                                        const int* __restrict__ bsum,
                                                        const int* __restrict__ deg,
                                                        float* __restrict__ dinv,
                                                        int n, int E, int nChunk) {
    __shared__ int wsum[4];
    __shared__ int soff[256];
    int tid = threadIdx.x;
    int lane = tid & 63, w = tid >> 6;
    int v = (tid < nChunk) ? bsum[tid] : 0;
    int s = v;
#pragma unroll
    for (int o = 1; o < 64; o <<= 1) { int t = __shfl_up(s, o); if (lane >= o) s += t; }
    if (lane == 63) wsum[w] = s;
    __syncthreads();
    int off = 0;
#pragma unroll
    for (int k = 0; k < 4; ++k) if (k < w) off += wsum[k];
    soff[tid] = s + off - v;                    // exclusive scan of bsum
    __syncthreads();
    int blockOff = soff[blockIdx.x];
    int i = blockIdx.x * 256 + tid;
    if (i < n) {
        rowptr[i] += blockOff;
        dinv[i] = rsqrtf((float)(deg[i] + 1));  // +1 = self loop
    }
    if (i == 0) rowptr[n] = E;
}

// pass 2: pure scatter, no atomics
__global__ void fill_kernel(const int* __restrict__ src, const int* __restrict__ dst,
                            const int* __restrict__ rank, const int* __restrict__ rowptr,
                            int* __restrict__ col, int E) {
    int e = blockIdx.x * 256 + threadIdx.x;
    if (e < E) col[rowptr[dst[e]] + rank[e]] = src[e];
}

// ---- MFMA GEMM: Hs[row] = bf16x2-packed (A @ W) * dinv[row] ----

template <int K, bool AF32>
__global__ __launch_bounds__(256) void gemm_mfma(const void* __restrict__ Aptr,
                                                 const uint32* __restrict__ Bt,
                                                 const float* __restrict__ dinv,
                                                 uint32* __restrict__ Hs, int N) {
    constexpr int KP2 = (K + 8) / 2;          // uints per padded row (68 / 52)
    __shared__ uint32 As[64 * KP2];
    __shared__ uint32 Bs[96 * KP2];
    int tid = threadIdx.x;
    int rowbase = blockIdx.x * 64;

    if constexpr (AF32) {
        const float* A = (const float*)Aptr;
        for (int f = tid; f < 64 * (K / 4); f += 256) {
            int r = f / (K / 4), q = f % (K / 4);
            int row = rowbase + r;
            float4 v = make_float4(0.f, 0.f, 0.f, 0.f);
            if (row < N) v = *reinterpret_cast<const float4*>(A + (size_t)row * K + q * 4);
            As[r * KP2 + q * 2]     = bf16_rne(v.x) | (bf16_rne(v.y) << 16);
            As[r * KP2 + q * 2 + 1] = bf16_rne(v.z) | (bf16_rne(v.w) << 16);
        }
    } else {
        const uint32* A = (const uint32*)Aptr;
        for (int f = tid; f < 64 * (K / 8); f += 256) {
            int r = f / (K / 8), s = f % (K / 8);
            int row = rowbase + r;
            uint4 v = make_uint4(0, 0, 0, 0);
            if (row < N) v = *reinterpret_cast<const uint4*>(A + (size_t)row * (K / 2) + s * 4);
            *reinterpret_cast<uint4*>(&As[r * KP2 + s * 4]) = v;
        }
    }
    for (int f = tid; f < 96 * KP2 / 4; f += 256) {
        *reinterpret_cast<uint4*>(&Bs[f * 4]) = *reinterpret_cast<const uint4*>(Bt + f * 4);
    }
    __syncthreads();

    int l = tid & 63, w = tid >> 6;
    int l15 = l & 15, lq = l >> 4;

    f32x4 acc[6];
#pragma unroll
    for (int j = 0; j < 6; ++j) acc[j] = (f32x4){0.f, 0.f, 0.f, 0.f};

    const uint32* arow = &As[(w * 16 + l15) * KP2 + lq * 4];   // k = lq*8
#pragma unroll
    for (int kc = 0; kc < K / 32; ++kc) {
        short8 a = *reinterpret_cast<const short8*>(arow + kc * 16);
#pragma unroll
        for (int j = 0; j < 6; ++j) {
            short8 b = *reinterpret_cast<const short8*>(&Bs[(j * 16 + l15) * KP2 + lq * 4 + kc * 16]);
            acc[j] = __builtin_amdgcn_mfma_f32_16x16x32_bf16(a, b, acc[j], 0, 0, 0);
        }
    }

#pragma unroll
    for (int r = 0; r < 4; ++r) {
        int row = rowbase + w * 16 + lq * 4 + r;
        float di = (row < N) ? dinv[row] : 0.f;
#pragma unroll
        for (int j = 0; j < 6; ++j) {
            float v = acc[j][r] * di;
            float vp = __shfl_xor(v, 1);
            if (row < N && !(l & 1)) {
                Hs[(size_t)row * 48 + (j * 16 + l15) / 2] = bf16_rne(v) | (bf16_rne(vp) << 16);
            }
        }
    }
}

// ---------- fused: aggregate (sym-norm) + bias + LayerNorm + PReLU ----------
// One wave = TWO nodes (2 x 32-lane halves); lane hl<24 owns 4 channels (dwordx2).
// R8 form: plain 8-deep batches, single clamped tail. (R9's dbuf+NT regressed.)

template <bool PACK_OUT>
__global__ __launch_bounds__(256) void agg_ln_prelu(const uint32* __restrict__ Hs,
                                                    const float* __restrict__ dinv,
                                                    const int* __restrict__ rowptr,
                                                    const int* __restrict__ col,
                                                    const float* __restrict__ bias,
                                                    const float* __restrict__ gamma,
                                                    const float* __restrict__ beta,
                                                    const float* __restrict__ alpha,
                                                    void* __restrict__ outv, int N) {
    int tid = threadIdx.x;
    int w = tid >> 6, lane = tid & 63;
    int half = lane >> 5, hl = lane & 31;
    int nodebase = blockIdx.x * 8 + w * 2;
    if (nodebase >= N) return;                 // both halves OOB
    int node = nodebase + half;
    int hc = min(hl, 23);                      // clamped channel-quad index
    bool active = (hl < 24) && (node < N);

    float a0 = 0.f, a1 = 0.f, a2 = 0.f, a3 = 0.f;   // even-t partials
    float b0 = 0.f, b1 = 0.f, b2 = 0.f, b3 = 0.f;   // odd-t partials

    int e0 = 0, e1 = 0;
    if (node < N) { e0 = rowptr[node]; e1 = rowptr[node + 1]; }
    const uint32* hp = Hs + 2 * hc;            // lane's column byte offset

    if (node < N) {
        uint2 us = *reinterpret_cast<const uint2*>(hp + (size_t)node * 48);   // self
        a0 = bf_lo(us.x); a1 = bf_hi(us.x); a2 = bf_lo(us.y); a3 = bf_hi(us.y);
    }

    int e = e0;
    // unclamped 8-deep batches (16 edges in flight per wave across both halves)
    for (; e + 8 <= e1; e += 8) {
        uint2 u[8];
#pragma unroll
        for (int t = 0; t < 8; ++t) {
            int j = col[e + t];                // uniform within half -> broadcast
            u[t] = *reinterpret_cast<const uint2*>(hp + (size_t)j * 48);
        }
#pragma unroll
        for (int t = 0; t < 8; ++t) {
            if (t & 1) { b0 += bf_lo(u[t].x); b1 += bf_hi(u[t].x); b2 += bf_lo(u[t].y); b3 += bf_hi(u[t].y); }
            else       { a0 += bf_lo(u[t].x); a1 += bf_hi(u[t].x); a2 += bf_lo(u[t].y); a3 += bf_hi(u[t].y); }
        }
    }
    // clamped masked tail
    if (e < e1) {
        uint2 u[8];
#pragma unroll
        for (int t = 0; t < 8; ++t) {
            int ee = min(e + t, e1 - 1);
            int j = col[ee];
            u[t] = *reinterpret_cast<const uint2*>(hp + (size_t)j * 48);
            if (e + t >= e1) { u[t].x = 0u; u[t].y = 0u; }
        }
#pragma unroll
        for (int t = 0; t < 8; ++t) {
            if (t & 1) { b0 += bf_lo(u[t].x); b1 += bf_hi(u[t].x); b2 += bf_lo(u[t].y); b3 += bf_hi(u[t].y); }
            else       { a0 += bf_lo(u[t].x); a1 += bf_hi(u[t].x); a2 += bf_lo(u[t].y); a3 += bf_hi(u[t].y); }
        }
    }

    float di = (node < N) ? dinv[node] : 0.f;
    float4 bs = *reinterpret_cast<const float4*>(bias + 4 * hc);
    float c0 = (a0 + b0) * di + bs.x;
    float c1 = (a1 + b1) * di + bs.y;
    float c2 = (a2 + b2) * di + bs.z;
    float c3 = (a3 + b3) * di + bs.w;

    // LayerNorm over 96 channels: butterfly within the 32-lane half
    float s1 = active ? (c0 + c1) + (c2 + c3) : 0.f;
    float s2 = active ? (c0 * c0 + c1 * c1) + (c2 * c2 + c3 * c3) : 0.f;
#pragma unroll
    for (int o = 16; o > 0; o >>= 1) {
        s1 += __shfl_xor(s1, o);
        s2 += __shfl_xor(s2, o);
    }

    if (active) {
        float mu = s1 * (1.f / 96.f);
        float var = s2 * (1.f / 96.f) - mu * mu;
        float rstd = rsqrtf(var + EPS);
        float4 gm = *reinterpret_cast<const float4*>(gamma + 4 * hc);
        float4 bt = *reinterpret_cast<const float4*>(beta + 4 * hc);
        float4 al = *reinterpret_cast<const float4*>(alpha + 4 * hc);
        float ln0 = (c0 - mu) * rstd * gm.x + bt.x;
        float ln1 = (c1 - mu) * rstd * gm.y + bt.y;
        float ln2 = (c2 - mu) * rstd * gm.z + bt.z;
        float ln3 = (c3 - mu) * rstd * gm.w + bt.w;
        float o0 = (ln0 >= 0.f) ? ln0 : al.x * ln0;
        float o1 = (ln1 >= 0.f) ? ln1 : al.y * ln1;
        float o2 = (ln2 >= 0.f) ? ln2 : al.z * ln2;
        float o3 = (ln3 >= 0.f) ? ln3 : al.w * ln3;
        if constexpr (PACK_OUT) {
            uint2 pv;
            pv.x = bf16_rne(o0) | (bf16_rne(o1) << 16);
            pv.y = bf16_rne(o2) | (bf16_rne(o3) << 16);
            *reinterpret_cast<uint2*>((uint32*)outv + (size_t)node * 48 + 2 * hl) = pv;
        } else {
            float4 ov; ov.x = o0; ov.y = o1; ov.z = o2; ov.w = o3;
            *reinterpret_cast<float4*>((float*)outv + (size_t)node * 96 + 4 * hl) = ov;
        }
    }
}

// ---------------- launch ----------------

extern "C" void kernel_launch(void* const* d_in, const int* in_sizes, int n_in,
                              void* d_out, int out_size, void* d_ws, size_t ws_size,
                              hipStream_t stream) {
    const float* x   = (const float*)d_in[0];
    const int*   ei  = (const int*)d_in[1];
    const float* W1  = (const float*)d_in[2];
    const float* b1  = (const float*)d_in[3];
    const float* W2  = (const float*)d_in[4];
    const float* b2  = (const float*)d_in[5];
    const float* g1  = (const float*)d_in[6];
    const float* be1 = (const float*)d_in[7];
    const float* g2  = (const float*)d_in[8];
    const float* be2 = (const float*)d_in[9];
    const float* a   = (const float*)d_in[10];

    const int N = in_sizes[0] / 128;       // 50000
    const int E = in_sizes[1] / 2;         // 800000
    const int* src = ei;
    const int* dst = ei + E;
    const int nScanBlocks = (N + 255) / 256;

    char* ws = (char*)d_ws;
    size_t off = 0;
    auto carve = [&](size_t bytes) -> void* {
        void* p = ws + off;
        off += (bytes + 255) & ~(size_t)255;
        return p;
    };
    int*    deg    = (int*)carve((size_t)N * 4);
    int*    rowptr = (int*)carve((size_t)(N + 1) * 4);
    int*    bsum   = (int*)carve((size_t)nScanBlocks * 4);
    float*  dinv   = (float*)carve((size_t)N * 4);
    int*    rank   = (int*)carve((size_t)E * 4);
    int*    col    = (int*)carve((size_t)E * 4);
    uint32* hbuf   = (uint32*)carve((size_t)N * 48 * 4);   // bf16x2 gather table
    uint32* w1bt   = (uint32*)carve((size_t)96 * 68 * 4);  // W1^T bf16 padded
    uint32* w2bt   = (uint32*)carve((size_t)96 * 52 * 4);  // W2^T bf16 padded
    uint32* p1     = (uint32*)d_out;   // layer-1 bf16x2 activations (front of d_out)
    float*  outp   = (float*)d_out;

    zero_wprep_kernel<<<nScanBlocks, 256, 0, stream>>>(deg, N, W1, w1bt, W2, w2bt);
    rank_kernel<<<(E + 255) / 256, 256, 0, stream>>>(dst, deg, rank, E);
    scan_blocks<<<nScanBlocks, 256, 0, stream>>>(deg, rowptr, bsum, N);
    finalize2_kernel<<<nScanBlocks, 256, 0, stream>>>(rowptr, bsum, deg, dinv, N, E, nScanBlocks);
    fill_kernel<<<(E + 255) / 256, 256, 0, stream>>>(src, dst, rank, rowptr, col, E);

    // layer 1
    gemm_mfma<128, true><<<(N + 63) / 64, 256, 0, stream>>>(x, w1bt, dinv, hbuf, N);
    agg_ln_prelu<true><<<(N + 7) / 8, 256, 0, stream>>>(hbuf, dinv, rowptr, col, b1, g1, be1, a, p1, N);
    // layer 2
    gemm_mfma<96, false><<<(N + 63) / 64, 256, 0, stream>>>(p1, w2bt, dinv, hbuf, N);
    agg_ln_prelu<false><<<(N + 7) / 8, 256, 0, stream>>>(hbuf, dinv, rowptr, col, b2, g2, be2, a, outp, N);
}